// Round 8
// baseline (135.521 us; speedup 1.0000x reference)
//
#include <hip/hip_runtime.h>

#define BS        64
#define W_TOTAL_C 2234368
#define B_TOTAL_C 3526

__device__ __forceinline__ float silu_f(float v) {
    return v / (1.f + __expf(-v));
}

// ---------------------------------------------------------------------------
// One layer, split-K, no cross-block sync (kernel boundaries order layers):
//  - EARLY: issue first 8 weight-row loads into named registers (latency
//    hides under the h-staging phase; rule #20: static names only)
//  - stage h-chunk into LDS; if PNK>0 h is rebuilt as
//    silu( sum_{k<PNK} prev_part[k][b][i] + prev_bias[i] )  (float2 loads)
//  - K-loop: iters 0..7 consume prefetched regs, 8..KC stream from HBM
//  - FINAL: tanh(a + bias) -> d_out ; else raw partial -> this layer's slice
// VEC=4 only where DOUT is a multiple of 4*BLK-coverage AND rows stay
// 16B-aligned (DOUT%4==0). All KC even except L0 (PNK==0 path).
template<int DIN, int DOUT, int KC, int NK, int PNK, int VEC, int BLK,
         bool FINAL, int WOFF, int PBOFF, int FBOFF>
__global__ __launch_bounds__(BLK)
void layer_kernel(const float* __restrict__ hin,   // x (PNK==0) or prev partials
                  const float* __restrict__ wbase,
                  const float* __restrict__ bias,
                  float* __restrict__ outp)        // partials slice, or d_out
{
    __shared__ float sh[KC];

    const int b   = blockIdx.z;
    const int ky  = blockIdx.y;
    const int k0  = ky * KC;
    const int tid = threadIdx.x;

    const int  o      = (blockIdx.x * BLK + tid) * VEC;
    const bool active = (o + VEC <= DOUT);   // even DOUT everywhere => no tail

    const float* wp = wbase + (size_t)b * W_TOTAL_C + WOFF
                            + (size_t)k0 * DOUT + o;

    // ---- EARLY weight prefetch: rows 0..7 into named registers ----
    float4 P0, P1, P2, P3, P4, P5, P6, P7;
    float2 Q0, Q1, Q2, Q3, Q4, Q5, Q6, Q7;
    if (active) {
        if (VEC == 4) {
            P0 = *reinterpret_cast<const float4*>(wp + (size_t)0 * DOUT);
            P1 = *reinterpret_cast<const float4*>(wp + (size_t)1 * DOUT);
            P2 = *reinterpret_cast<const float4*>(wp + (size_t)2 * DOUT);
            P3 = *reinterpret_cast<const float4*>(wp + (size_t)3 * DOUT);
            P4 = *reinterpret_cast<const float4*>(wp + (size_t)4 * DOUT);
            P5 = *reinterpret_cast<const float4*>(wp + (size_t)5 * DOUT);
            P6 = *reinterpret_cast<const float4*>(wp + (size_t)6 * DOUT);
            P7 = *reinterpret_cast<const float4*>(wp + (size_t)7 * DOUT);
        } else {
            Q0 = *reinterpret_cast<const float2*>(wp + (size_t)0 * DOUT);
            Q1 = *reinterpret_cast<const float2*>(wp + (size_t)1 * DOUT);
            Q2 = *reinterpret_cast<const float2*>(wp + (size_t)2 * DOUT);
            Q3 = *reinterpret_cast<const float2*>(wp + (size_t)3 * DOUT);
            Q4 = *reinterpret_cast<const float2*>(wp + (size_t)4 * DOUT);
            Q5 = *reinterpret_cast<const float2*>(wp + (size_t)5 * DOUT);
            Q6 = *reinterpret_cast<const float2*>(wp + (size_t)6 * DOUT);
            Q7 = *reinterpret_cast<const float2*>(wp + (size_t)7 * DOUT);
        }
    }

    // ---- stage h chunk (fused prev-layer reduce + bias + silu) ----
    if (PNK == 0) {
        for (int i = tid; i < KC; i += BLK)
            sh[i] = hin[b * DIN + k0 + i];
    } else {
        for (int i2 = tid; i2 < KC / 2; i2 += BLK) {
            const int i = i2 * 2;
            float2 s2 = *reinterpret_cast<const float2*>(
                            &bias[b * B_TOTAL_C + PBOFF + k0 + i]);
            #pragma unroll
            for (int k = 0; k < PNK; ++k) {
                const float2 p2 = *reinterpret_cast<const float2*>(
                    &hin[((size_t)k * BS + b) * DIN + k0 + i]);
                s2.x += p2.x;
                s2.y += p2.y;
            }
            sh[i]     = silu_f(s2.x);
            sh[i + 1] = silu_f(s2.y);
        }
    }
    __syncthreads();

    if (!active) return;

    float a0 = 0.f, a1 = 0.f, a2 = 0.f, a3 = 0.f;

    if (VEC == 4) {
        a0 = fmaf(sh[0], P0.x, a0); a1 = fmaf(sh[0], P0.y, a1);
        a2 = fmaf(sh[0], P0.z, a2); a3 = fmaf(sh[0], P0.w, a3);
        a0 = fmaf(sh[1], P1.x, a0); a1 = fmaf(sh[1], P1.y, a1);
        a2 = fmaf(sh[1], P1.z, a2); a3 = fmaf(sh[1], P1.w, a3);
        a0 = fmaf(sh[2], P2.x, a0); a1 = fmaf(sh[2], P2.y, a1);
        a2 = fmaf(sh[2], P2.z, a2); a3 = fmaf(sh[2], P2.w, a3);
        a0 = fmaf(sh[3], P3.x, a0); a1 = fmaf(sh[3], P3.y, a1);
        a2 = fmaf(sh[3], P3.z, a2); a3 = fmaf(sh[3], P3.w, a3);
        a0 = fmaf(sh[4], P4.x, a0); a1 = fmaf(sh[4], P4.y, a1);
        a2 = fmaf(sh[4], P4.z, a2); a3 = fmaf(sh[4], P4.w, a3);
        a0 = fmaf(sh[5], P5.x, a0); a1 = fmaf(sh[5], P5.y, a1);
        a2 = fmaf(sh[5], P5.z, a2); a3 = fmaf(sh[5], P5.w, a3);
        a0 = fmaf(sh[6], P6.x, a0); a1 = fmaf(sh[6], P6.y, a1);
        a2 = fmaf(sh[6], P6.z, a2); a3 = fmaf(sh[6], P6.w, a3);
        a0 = fmaf(sh[7], P7.x, a0); a1 = fmaf(sh[7], P7.y, a1);
        a2 = fmaf(sh[7], P7.z, a2); a3 = fmaf(sh[7], P7.w, a3);
        #pragma unroll 8
        for (int i = 8; i < KC; ++i) {
            const float hv = sh[i];
            const float4 w = *reinterpret_cast<const float4*>(wp + (size_t)i * DOUT);
            a0 = fmaf(hv, w.x, a0);
            a1 = fmaf(hv, w.y, a1);
            a2 = fmaf(hv, w.z, a2);
            a3 = fmaf(hv, w.w, a3);
        }
    } else {
        a0 = fmaf(sh[0], Q0.x, a0); a1 = fmaf(sh[0], Q0.y, a1);
        a0 = fmaf(sh[1], Q1.x, a0); a1 = fmaf(sh[1], Q1.y, a1);
        a0 = fmaf(sh[2], Q2.x, a0); a1 = fmaf(sh[2], Q2.y, a1);
        a0 = fmaf(sh[3], Q3.x, a0); a1 = fmaf(sh[3], Q3.y, a1);
        a0 = fmaf(sh[4], Q4.x, a0); a1 = fmaf(sh[4], Q4.y, a1);
        a0 = fmaf(sh[5], Q5.x, a0); a1 = fmaf(sh[5], Q5.y, a1);
        a0 = fmaf(sh[6], Q6.x, a0); a1 = fmaf(sh[6], Q6.y, a1);
        a0 = fmaf(sh[7], Q7.x, a0); a1 = fmaf(sh[7], Q7.y, a1);
        #pragma unroll 8
        for (int i = 8; i < KC; ++i) {
            const float hv = sh[i];
            const float2 w = *reinterpret_cast<const float2*>(wp + (size_t)i * DOUT);
            a0 = fmaf(hv, w.x, a0);
            a1 = fmaf(hv, w.y, a1);
        }
    }

    if (FINAL) {
        if (o + 0 < DOUT)
            outp[b * DOUT + o + 0] = tanhf(a0 + bias[b * B_TOTAL_C + FBOFF + o + 0]);
        if (o + 1 < DOUT)
            outp[b * DOUT + o + 1] = tanhf(a1 + bias[b * B_TOTAL_C + FBOFF + o + 1]);
        if (VEC == 4) {
            if (o + 2 < DOUT)
                outp[b * DOUT + o + 2] = tanhf(a2 + bias[b * B_TOTAL_C + FBOFF + o + 2]);
            if (o + 3 < DOUT)
                outp[b * DOUT + o + 3] = tanhf(a3 + bias[b * B_TOTAL_C + FBOFF + o + 3]);
        }
    } else {
        float* pp = outp + ((size_t)ky * BS + b) * DOUT + o;
        if (VEC == 4) *reinterpret_cast<float4*>(pp) = make_float4(a0, a1, a2, a3);
        else          *reinterpret_cast<float2*>(pp) = make_float2(a0, a1);
    }
}

// ---------------------------------------------------------------------------
extern "C" void kernel_launch(void* const* d_in, const int* in_sizes, int n_in,
                              void* d_out, int out_size, void* d_ws, size_t ws_size,
                              hipStream_t stream)
{
    const float* x    = (const float*)d_in[0];   // [64][1862]
    const float* wts  = (const float*)d_in[1];   // [64][W_TOTAL]
    const float* bias = (const float*)d_in[2];   // [64][B_TOTAL]
    float* out = (float*)d_out;                  // [64][1862]

    // partial slices (floats); every slot written before read within one call
    float* p0 = (float*)d_ws;        // 14*64*512 = 458752
    float* p1 = p0 + 458752;         //  4*64*256 =  65536
    float* p2 = p1 + 65536;          //  4*64*128 =  32768
    float* p3 = p2 + 32768;          //  4*64*256 =  65536
    float* p4 = p3 + 65536;          //  4*64*512 = 131072   (~3.0 MB total)

    // L0: 1862 -> 512  x -> p0    aligned float4, NK=14; grid 1x14x64,
    //     BLK=128 -> exact coverage 128*4 = 512; 1792 waves (7/CU)
    layer_kernel<1862, 512, 133, 14, 0, 4, 128, false,       0,    0,    0>
        <<<dim3(1, 14, BS), 128, 0, stream>>>(x, wts, bias, p0);
    // L1: 512 -> 256   p0 -> p1   R3 config (PNK=14 now): BLK=128, VEC=2
    layer_kernel< 512, 256, 128,  4, 14, 2, 128, false,  953344,    0,    0>
        <<<dim3(1, 4, BS), 128, 0, stream>>>(p0, wts, bias, p1);
    // L2: 256 -> 128   p1 -> p2   R3 exact: BLK=64, VEC=2, KC=64
    layer_kernel< 256, 128,  64,  4,  4, 2, 64, false, 1084416,  512,    0>
        <<<dim3(1, 4, BS), 64, 0, stream>>>(p1, wts, bias, p2);
    // L3: 128 -> 256   p2 -> p3   R3 exact: BLK=128, VEC=2, KC=32
    layer_kernel< 128, 256,  32,  4,  4, 2, 128, false, 1117184,  768,    0>
        <<<dim3(1, 4, BS), 128, 0, stream>>>(p2, wts, bias, p3);
    // L4: 256 -> 512   p3 -> p4   R3 exact: BLK=128, VEC=2, KC=64
    layer_kernel< 256, 512,  64,  4,  4, 2, 128, false, 1149952,  896,    0>
        <<<dim3(2, 4, BS), 128, 0, stream>>>(p3, wts, bias, p4);
    // L5: 512 -> 1862  p4 -> out  R3 exact: full-K, BLK=128, VEC=2
    layer_kernel< 512, 1862, 512,  1,  4, 2, 128, true, 1281024, 1152, 1664>
        <<<dim3(8, 1, BS), 128, 0, stream>>>(p4, wts, bias, out);
}

// Round 9
// 122.310 us; speedup vs baseline: 1.1080x; 1.1080x over previous
//
#include <hip/hip_runtime.h>

#define BS        64
#define W_TOTAL_C 2234368
#define B_TOTAL_C 3526

__device__ __forceinline__ float silu_f(float v) {
    return v / (1.f + __expf(-v));
}

// ---------------------------------------------------------------------------
// One layer, split-K, NO cross-block sync:
//   - stage h-chunk into LDS; if PNK>0, h is reconstructed as
//     silu( sum_{k<PNK} prev_part[k][b][i] + prev_bias[i] )
//   - K-loop: a[j] += sh[i] * W[b][k0+i][o+j]   (coalesced float2 weight loads)
//   - if FINAL: write tanh(a + bias) straight to d_out
//     else:     write raw partial to this layer's slice (plain stores)
// Visibility across layers comes from kernel boundaries on the stream.
template<int DIN, int DOUT, int KC, int NK, int PNK, int VEC, int BLK,
         bool FINAL, int WOFF, int PBOFF, int FBOFF>
__global__ __launch_bounds__(BLK)
void layer_kernel(const float* __restrict__ hin,   // x (PNK==0) or prev partials
                  const float* __restrict__ wbase,
                  const float* __restrict__ bias,
                  float* __restrict__ outp)        // this layer's partials, or d_out
{
    __shared__ float sh[KC];

    const int b   = blockIdx.z;
    const int ky  = blockIdx.y;
    const int k0  = ky * KC;
    const int tid = threadIdx.x;

    // ---- stage h chunk (fuse prev layer's reduction + bias + silu) ----
    for (int i = tid; i < KC; i += BLK) {
        float s;
        if (PNK == 0) {
            s = hin[b * DIN + k0 + i];
        } else {
            s = bias[b * B_TOTAL_C + PBOFF + k0 + i];
            #pragma unroll
            for (int k = 0; k < PNK; ++k)
                s += hin[((size_t)k * BS + b) * DIN + k0 + i];
            s = silu_f(s);
        }
        sh[i] = s;
    }
    __syncthreads();

    const int  o      = (blockIdx.x * BLK + tid) * VEC;
    const bool active = (o < DOUT);

    float a0 = 0.f, a1 = 0.f;
    if (active) {
        const float* wp = wbase + (size_t)b * W_TOTAL_C + WOFF
                                + (size_t)k0 * DOUT + o;
        #pragma unroll 16
        for (int i = 0; i < KC; ++i) {
            const float hv = sh[i];
            const float2 w = *reinterpret_cast<const float2*>(wp);
            a0 = fmaf(hv, w.x, a0);
            a1 = fmaf(hv, w.y, a1);
            wp += DOUT;
        }
    }

    if (!active) return;

    if (FINAL) {
        float v0 = a0 + bias[b * B_TOTAL_C + FBOFF + o];
        outp[b * DOUT + o] = tanhf(v0);
        if (o + 1 < DOUT) {
            float v1 = a1 + bias[b * B_TOTAL_C + FBOFF + o + 1];
            outp[b * DOUT + o + 1] = tanhf(v1);
        }
    } else {
        float* pp = outp + ((size_t)ky * BS + b) * DOUT + o;
        pp[0] = a0;
        pp[1] = a1;
    }
}

// ---------------------------------------------------------------------------
extern "C" void kernel_launch(void* const* d_in, const int* in_sizes, int n_in,
                              void* d_out, int out_size, void* d_ws, size_t ws_size,
                              hipStream_t stream)
{
    const float* x    = (const float*)d_in[0];   // [64][1862]
    const float* wts  = (const float*)d_in[1];   // [64][W_TOTAL]
    const float* bias = (const float*)d_in[2];   // [64][B_TOTAL]
    float* out = (float*)d_out;                  // [64][1862]

    // partial slices (floats), all plain-store/plain-load, written before read
    float* p0 = (float*)d_ws;        // 7*64*512  = 229376
    float* p1 = p0 + 229376;         // 4*64*256  =  65536
    float* p2 = p1 + 65536;          // 4*64*128  =  32768
    float* p3 = p2 + 32768;          // 4*64*256  =  65536
    float* p4 = p3 + 65536;          // 4*64*512  = 131072  (total 524288 f = 2 MB)

    // L0: 1862 -> 512   (reads x; writes p0)       grid 2x7x64 = 896 blocks
    layer_kernel<1862, 512, 266, 7, 0, 2, 128, false,       0,    0,    0>
        <<<dim3(2, 7, BS), 128, 0, stream>>>(x, wts, bias, p0);
    // L1: 512 -> 256    (reduce p0 + silu; writes p1)  grid 1x4x64 = 256
    layer_kernel< 512, 256, 128, 4, 7, 2, 128, false,  953344,    0,    0>
        <<<dim3(1, 4, BS), 128, 0, stream>>>(p0, wts, bias, p1);
    // L2: 256 -> 128    (reduce p1; writes p2)          grid 1x4x64 = 256
    layer_kernel< 256, 128,  64, 4, 4, 2,  64, false, 1084416,  512,    0>
        <<<dim3(1, 4, BS),  64, 0, stream>>>(p1, wts, bias, p2);
    // L3: 128 -> 256    (reduce p2; writes p3)          grid 1x4x64 = 256
    layer_kernel< 128, 256,  32, 4, 4, 2, 128, false, 1117184,  768,    0>
        <<<dim3(1, 4, BS), 128, 0, stream>>>(p2, wts, bias, p3);
    // L4: 256 -> 512    (reduce p3; writes p4)          grid 2x4x64 = 512
    layer_kernel< 256, 512,  64, 4, 4, 2, 128, false, 1149952,  896,    0>
        <<<dim3(2, 4, BS), 128, 0, stream>>>(p3, wts, bias, p4);
    // L5: 512 -> 1862   (reduce p4; bias+tanh; writes d_out)  grid 8x1x64 = 512
    layer_kernel< 512, 1862, 512, 1, 4, 2, 128, true, 1281024, 1152, 1664>
        <<<dim3(8, 1, BS), 128, 0, stream>>>(p4, wts, bias, out);
}